// Round 15
// baseline (39.295 us; speedup 1.0000x reference)
//
#include <hip/hip_runtime.h>

typedef __attribute__((ext_vector_type(8))) short short8;
typedef __attribute__((ext_vector_type(4))) float f32x4;
typedef __attribute__((ext_vector_type(4))) unsigned int u32x4;
typedef unsigned short ushort_t;

#define BB 4
#define HW 3136
#define NX (4*256*3136)          // total x elements

// k2 LDS regions (4-row tile): h 224*128 @0 ; b2s @28672
// wgt bf16 [64][232] @0 (aliases h after phase B; max byte 22718)
#define K2_B2S 28672
#define K2_TOT 28928

__device__ __forceinline__ unsigned int f2bf(float f) {
    unsigned int u = __float_as_uint(f);
    return (u + 0x7FFFu + ((u >> 16) & 1u)) >> 16;   // RNE to bf16 bits
}

__device__ __forceinline__ u32x4 pack8(f32x4 lo, f32x4 hi) {
    u32x4 r;
    r[0] = f2bf(lo[0]) | (f2bf(lo[1]) << 16);
    r[1] = f2bf(lo[2]) | (f2bf(lo[3]) << 16);
    r[2] = f2bf(hi[0]) | (f2bf(hi[1]) << 16);
    r[3] = f2bf(hi[2]) | (f2bf(hi[3]) << 16);
    return r;
}

// k1: h = relu(conv1+bn) via bf16 MFMA — LDS-free, barrier-free.
// 896 blocks = (b, 14-px quarter-row). 4 waves; wave wd owns o-block wd*16..+15.
// M=16 (14 used), N=16/wave, K=256. A (x) and B (w1, BN-folded) fragments are
// read directly from global each K-step; 3.5 waves/SIMD of TLP hides latency.
__global__ __launch_bounds__(256) void k1_mfma(
        const float* __restrict__ x, const float* __restrict__ w1,
        const float* __restrict__ gamma, const float* __restrict__ beta,
        const float* __restrict__ mean, const float* __restrict__ var,
        ushort_t* __restrict__ h_g) {
    int blk = blockIdx.x;
    int b = blk / 224, q = blk % 224;
    int px0 = q * 14;                       // 224*14 = 3136 exactly
    int tid = threadIdx.x;
    int lane = tid & 63, wd = tid >> 6;

    int o = wd * 16 + (lane & 15);          // this lane's B-row AND D-col
    float sc = gamma[o] * rsqrtf(var[o] + 1e-5f);
    float bo = beta[o] - mean[o] * sc;

    int pxa = min(px0 + (lane & 15), HW - 1);   // A-row; pad rows 14/15 clamped
    const float* xb = x + (size_t)b * 256 * HW + pxa;
    const float* wrow = w1 + (size_t)o * 256;
    int kb = (lane >> 4) << 3;              // k-element offset within 32-chunk

    f32x4 acc = {0.f, 0.f, 0.f, 0.f};
#pragma unroll 2
    for (int ks = 0; ks < 8; ks++) {
        int kc = ks * 32 + kb;
        f32x4 blo = *(const f32x4*)(wrow + kc);
        f32x4 bhi = *(const f32x4*)(wrow + kc + 4);
        float xa[8];
#pragma unroll
        for (int u = 0; u < 8; u++) xa[u] = xb[(size_t)(kc + u) * HW];

        u32x4 av;
#pragma unroll
        for (int j = 0; j < 4; j++)
            av[j] = f2bf(xa[2 * j]) | (f2bf(xa[2 * j + 1]) << 16);
        f32x4 bls = {blo[0] * sc, blo[1] * sc, blo[2] * sc, blo[3] * sc};
        f32x4 bhs = {bhi[0] * sc, bhi[1] * sc, bhi[2] * sc, bhi[3] * sc};
        u32x4 bv = pack8(bls, bhs);

        acc = __builtin_amdgcn_mfma_f32_16x16x32_bf16(
                __builtin_bit_cast(short8, av), __builtin_bit_cast(short8, bv),
                acc, 0, 0, 0);
    }

    // D: row(px) = (lane>>4)*4 + r, col(o) = lane&15 (+wd*16) — proven mapping
#pragma unroll
    for (int r = 0; r < 4; r++) {
        int pxr = ((lane >> 4) << 2) + r;
        if (pxr < 14) {
            float v = fmaxf(acc[r] + bo, 0.f);
            h_g[((size_t)b * HW + px0 + pxr) * 64 + o] = (ushort_t)f2bf(v);
        }
    }
}

// k2: fused weight-GEMM (bf16 MFMA, A-fragments direct from global) + involution.
// Round-12 version verbatim (best measured: 32.8 µs total).
__global__ __launch_bounds__(256, 4) void k2_fused(
        const float* __restrict__ x, const ushort_t* __restrict__ h_g,
        const float* __restrict__ w2, const float* __restrict__ b2,
        float* __restrict__ out) {
    __shared__ __align__(16) char lds[K2_TOT];
    int wid0 = blockIdx.x;
    int xcd = wid0 & 7, pos = wid0 >> 3;
    int work = xcd * 112 + pos;
    int b = work / 224;
    int rem = work - b * 224;
    int half = rem / 112, r2 = rem - half * 112;
    int tloc = r2 >> 4, g = r2 & 15;
    int tile = half * 7 + tloc;                    // 0..13, rows [tile*4, tile*4+4)
    int tid = threadIdx.x;
    int lane = tid & 63, wd = tid >> 6;

    // ---- A-fragments: w2 rows direct from global (L2-resident), issued first.
    int arow = wd * 16 + (lane & 15);
    int wrow = min(g * 49 + arow, 783);
    const float* wsrc = w2 + (size_t)wrow * 64 + ((lane >> 4) << 3);
    f32x4 a0lo = *(const f32x4*)(wsrc);
    f32x4 a0hi = *(const f32x4*)(wsrc + 4);
    f32x4 a1lo = *(const f32x4*)(wsrc + 32);
    f32x4 a1hi = *(const f32x4*)(wsrc + 36);

    // ---- Phase A1: stage h tile (224 px rows x 64c bf16), XOR-swizzled ----
    const char* hg = (const char*)h_g + ((size_t)b * HW + tile * 224) * 128;
    for (int i = tid; i < 1792; i += 256) {
        int row = i >> 3, cb = (i & 7) << 4;
        u32x4 v = *(const u32x4*)(hg + row * 128 + cb);
        *(u32x4*)(lds + row * 128 + (cb ^ ((row & 7) << 4))) = v;
    }
    if (tid < 49) ((float*)(lds + K2_B2S))[tid] = b2[g * 49 + tid];

    u32x4 ap[2];
    ap[0] = pack8(a0lo, a0hi);
    ap[1] = pack8(a1lo, a1hi);
    __syncthreads();

    // ---- Phase B: wgt[64tap][224px] = w2(64x64) @ h(64c x 224px) via MFMA ----
    f32x4 acc[14];
#pragma unroll
    for (int n = 0; n < 14; n++) acc[n] = (f32x4){0.f, 0.f, 0.f, 0.f};
#pragma unroll
    for (int ks = 0; ks < 2; ks++) {
        int kc = ks * 64 + ((lane >> 4) << 4);
        short8 a = __builtin_bit_cast(short8, ap[ks]);
#pragma unroll
        for (int n = 0; n < 14; n++) {
            int brow = n * 16 + (lane & 15);
            short8 bb = *(const short8*)(lds + brow * 128 + (kc ^ ((brow & 7) << 4)));
            acc[n] = __builtin_amdgcn_mfma_f32_16x16x32_bf16(a, bb, acc[n], 0, 0, 0);
        }
    }
    __syncthreads();    // all B-reads done before overwriting h with wgt

    // ---- Epilogue: wgt bf16 [64][232] @0 (aliases h), +bias ----
    {
        const float* b2s = (const float*)(lds + K2_B2S);
        ushort_t* wl = (ushort_t*)lds;
#pragma unroll
        for (int n = 0; n < 14; n++) {
#pragma unroll
            for (int rr = 0; rr < 4; rr++) {
                int tap = wd * 16 + ((lane >> 4) << 2) + rr;
                if (tap < 49) {
                    int px = n * 16 + (lane & 15);
                    wl[tap * 232 + px] = (ushort_t)f2bf(acc[n][rr] + b2s[tap]);
                }
            }
        }
    }
    __syncthreads();

    // ---- Phase D: involution. thread = (2 channels, 8 contiguous px) ----
    int cpk = tid >> 5;            // 0..7 channel-pair
    int pg = tid & 31;
    int py = pg >> 3, xi = pg & 7; // 4 rows x 7 octets (xi<7 active)
    if (xi < 7) {
        int x0 = xi * 8;
        int c0 = g * 16 + cpk * 2;
        int rowb = tile * 4 + py;
        float accd[2][8];
#pragma unroll
        for (int cc = 0; cc < 2; cc++)
#pragma unroll
            for (int pi = 0; pi < 8; pi++) accd[cc][pi] = 0.f;

        for (int ky = 0; ky < 7; ky++) {
            int rr = rowb + ky - 3;
            if (rr < 0 || rr >= 56) continue;      // zero-pad rows contribute 0
            float w[2][16];
#pragma unroll
            for (int cc = 0; cc < 2; cc++) {
                int base = (b * 256 + c0 + cc) * HW + rr * 56 + x0 - 4;
#pragma unroll
                for (int k4 = 0; k4 < 4; k4++) {
                    int o = base + k4 * 4;
                    o = min(max(o, 0), NX - 4);    // clamp; OOB values zeroed below
                    *(f32x4*)&w[cc][k4 * 4] = *(const f32x4*)(x + o);
                }
            }
            if (x0 == 0) {                          // img cols < 0
#pragma unroll
                for (int cc = 0; cc < 2; cc++) { w[cc][1] = w[cc][2] = w[cc][3] = 0.f; }
            }
            if (x0 == 48) {                         // img cols > 55
#pragma unroll
                for (int cc = 0; cc < 2; cc++) { w[cc][12] = w[cc][13] = w[cc][14] = 0.f; }
            }
#pragma unroll
            for (int kx = 0; kx < 7; kx++) {
                u32x4 wv = *(const u32x4*)(lds + ((ky * 7 + kx) * 232 + py * 56 + x0) * 2);
                float wf[8];
#pragma unroll
                for (int j = 0; j < 4; j++) {
                    wf[2 * j]     = __uint_as_float(wv[j] << 16);
                    wf[2 * j + 1] = __uint_as_float(wv[j] & 0xFFFF0000u);
                }
#pragma unroll
                for (int cc = 0; cc < 2; cc++)
#pragma unroll
                    for (int pi = 0; pi < 8; pi++)
                        accd[cc][pi] = fmaf(wf[pi], w[cc][pi + kx + 1], accd[cc][pi]);
            }
        }
#pragma unroll
        for (int cc = 0; cc < 2; cc++) {
            float* op = out + (size_t)(b * 256 + c0 + cc) * HW + tile * 224 + py * 56 + x0;
            *(f32x4*)op = (f32x4){accd[cc][0], accd[cc][1], accd[cc][2], accd[cc][3]};
            *(f32x4*)(op + 4) = (f32x4){accd[cc][4], accd[cc][5], accd[cc][6], accd[cc][7]};
        }
    }
}

extern "C" void kernel_launch(void* const* d_in, const int* in_sizes, int n_in,
                              void* d_out, int out_size, void* d_ws, size_t ws_size,
                              hipStream_t stream) {
    const float* x     = (const float*)d_in[0];
    const float* w1    = (const float*)d_in[1];
    const float* gamma = (const float*)d_in[2];
    const float* beta  = (const float*)d_in[3];
    const float* mean  = (const float*)d_in[4];
    const float* var   = (const float*)d_in[5];
    const float* w2    = (const float*)d_in[6];
    const float* b2    = (const float*)d_in[7];
    float* out = (float*)d_out;

    ushort_t* h_g = (ushort_t*)d_ws;               // [B][3136][64] bf16 = 1.6 MB

    k1_mfma<<<896, 256, 0, stream>>>(x, w1, gamma, beta, mean, var, h_g);
    k2_fused<<<896, 256, 0, stream>>>(x, h_g, w2, b2, out);
}